// Round 1
// baseline (757.940 us; speedup 1.0000x reference)
//
#include <hip/hip_runtime.h>
#include <cstdint>

// Problem constants
#define DM   512      // D_MODEL
#define DFF  2048     // D_FF
#define BSZ  4        // batch
#define LSEQ 1024     // sequence length

// ---------- small float4 helpers ----------
__device__ __forceinline__ float4 f4fma(float4 a, float4 b, float4 c) {
    return make_float4(fmaf(a.x, b.x, c.x), fmaf(a.y, b.y, c.y),
                       fmaf(a.z, b.z, c.z), fmaf(a.w, b.w, c.w));
}
__device__ __forceinline__ float4 f4mul(float4 a, float4 b) {
    return make_float4(a.x * b.x, a.y * b.y, a.z * b.z, a.w * b.w);
}

// =====================================================================
// Kernel 1: the STP scan, fused with the W1 projection.
//
// grid = BSZ * (DFF/16) = 512 blocks, block = 256 threads (4 waves).
// Block: b = blockIdx.x >> 7, fbase = (blockIdx.x & 127)*16.
// Wave w owns rows f = fbase + w*4 + g  (g = lane>>4), 16 lanes per row.
// Lane j = lane&15 owns d-elements d = 4j + 64k + c (k=0..7, c=0..3),
// i.e. float4 index j + 16k of the 512-float row.
//
// State per lane (float4[8] each): FW = F + W1row, R = retention,
// G = Gamma, WR = (1-R)*W1row.  F0 = 0  =>  FW0 = W1row.
//   h_pre = FW·x + b1
//   FW'   = R∘FW + WR + (G∘x)*h_pre
// x_t staged per block in double-buffered LDS (2KB per buffer).
// Writes h = gelu(h_pre) to hbuf[(b*L + t)*DFF + f]  (GEMM2's A matrix).
// =====================================================================
__global__ __launch_bounds__(256, 2)
void stp_scan(const float* __restrict__ x,     // (B, L, DM)
              const float* __restrict__ W1,    // (DFF, DM)
              const float* __restrict__ b1,    // (DFF)
              const float* __restrict__ Lam,   // (DFF, DM)
              const float* __restrict__ Gam,   // (DFF, DM)
              float* __restrict__ hbuf)        // (B*L, DFF)
{
    const int tid  = threadIdx.x;
    const int lane = tid & 63;
    const int w    = tid >> 6;
    const int j    = lane & 15;
    const int g    = lane >> 4;
    const int b    = blockIdx.x >> 7;
    const int fbase = (blockIdx.x & 127) << 4;
    const int f    = fbase + w * 4 + g;

    __shared__ float4 xs[2][128];   // 2 x 512 floats

    const float4* __restrict__ x4 =
        reinterpret_cast<const float4*>(x + (size_t)b * LSEQ * DM);

    float4 FW[8], R[8], G[8], WR[8];
    {
        const float4* lr = reinterpret_cast<const float4*>(Lam + (size_t)f * DM);
        const float4* gr = reinterpret_cast<const float4*>(Gam + (size_t)f * DM);
        const float4* wr = reinterpret_cast<const float4*>(W1  + (size_t)f * DM);
        #pragma unroll
        for (int k = 0; k < 8; ++k) {
            const int idx = j + 16 * k;
            float4 lv = lr[idx];
            float4 rv;
            rv.x = 1.0f / (1.0f + expf(lv.x));   // retention = 1 - sigmoid(l) = 1/(1+e^l)
            rv.y = 1.0f / (1.0f + expf(lv.y));
            rv.z = 1.0f / (1.0f + expf(lv.z));
            rv.w = 1.0f / (1.0f + expf(lv.w));
            R[k] = rv;
            G[k] = gr[idx];
            float4 wv = wr[idx];
            FW[k] = wv;                           // F=0 -> FW = W1row
            WR[k].x = wv.x * (1.0f - rv.x);
            WR[k].y = wv.y * (1.0f - rv.y);
            WR[k].z = wv.z * (1.0f - rv.z);
            WR[k].w = wv.w * (1.0f - rv.w);
        }
    }
    const float b1v = b1[f];

    // prologue: stage x[0]
    if (tid < 128) xs[0][tid] = x4[tid];
    __syncthreads();

    float* __restrict__ hout = hbuf + (size_t)b * LSEQ * DFF + f;

    #pragma unroll 1
    for (int t = 0; t < LSEQ; ++t) {
        const int cur = t & 1;

        // issue next x_t load early (consumed by ds_write at loop bottom)
        float4 stage;
        const bool do_stage = ((t + 1) < LSEQ) && (tid < 128);
        if (do_stage) stage = x4[(t + 1) * 128 + tid];

        // x fragment from LDS
        float4 xr[8];
        #pragma unroll
        for (int k = 0; k < 8; ++k) xr[k] = xs[cur][j + 16 * k];

        // dot(FW, x): 32 fma/lane, 2 chains for ILP
        float4 a0 = make_float4(0.f, 0.f, 0.f, 0.f);
        float4 a1 = make_float4(0.f, 0.f, 0.f, 0.f);
        #pragma unroll
        for (int k = 0; k < 8; k += 2) {
            a0 = f4fma(FW[k],     xr[k],     a0);
            a1 = f4fma(FW[k + 1], xr[k + 1], a1);
        }
        float p = (a0.x + a1.x) + (a0.y + a1.y) + (a0.z + a1.z) + (a0.w + a1.w);

        // reduce across the 16 lanes of this row
        p += __shfl_xor(p, 1);
        p += __shfl_xor(p, 2);
        p += __shfl_xor(p, 4);
        p += __shfl_xor(p, 8);

        const float hp = p + b1v;

        // exact gelu (output only; does NOT feed the recurrence)
        const float hg = 0.5f * hp * (1.0f + erff(hp * 0.70710678118654752f));

        // FW' = R*FW + WR + (G*x)*hp   (3 VALU/elem)
        #pragma unroll
        for (int k = 0; k < 8; ++k) {
            float4 gx = f4mul(G[k], xr[k]);
            float4 s;
            s.x = fmaf(gx.x, hp, WR[k].x);
            s.y = fmaf(gx.y, hp, WR[k].y);
            s.z = fmaf(gx.z, hp, WR[k].z);
            s.w = fmaf(gx.w, hp, WR[k].w);
            FW[k] = f4fma(R[k], FW[k], s);
        }

        if (j == 0) hout[(size_t)t * DFF] = hg;

        // late ds_write of the prefetched x, then one barrier per step
        if (do_stage) xs[cur ^ 1][tid] = stage;
        __syncthreads();
    }
}

// =====================================================================
// Kernel 2: C[M,N] = A[M,K] · B[N,K]^T + bias[N]   (fp32, NT, all dims
// multiples of tile). 64x64 tile, BK=16, 256 threads, 4x4 per thread.
// =====================================================================
__global__ __launch_bounds__(256)
void gemm_nt_bias(const float* __restrict__ A,
                  const float* __restrict__ Bm,
                  const float* __restrict__ bias,
                  float* __restrict__ C,
                  int M, int N, int K)
{
    __shared__ float As[16][68];   // [k][m], +4 pad keeps float4 alignment
    __shared__ float Bs[16][68];   // [k][n]

    const int tid = threadIdx.x;
    const int tx  = tid & 15;
    const int ty  = tid >> 4;
    const int row0 = blockIdx.y * 64;
    const int col0 = blockIdx.x * 64;

    const int lr = tid >> 2;          // 0..63: row within tile
    const int lk = (tid & 3) << 2;    // 0,4,8,12: k offset

    const float* Aptr = A  + (size_t)(row0 + lr) * K + lk;
    const float* Bptr = Bm + (size_t)(col0 + lr) * K + lk;

    float acc[4][4] = {};
    float4 av = *reinterpret_cast<const float4*>(Aptr);
    float4 bv = *reinterpret_cast<const float4*>(Bptr);

    const int NT = K >> 4;
    for (int kt = 0; kt < NT; ++kt) {
        __syncthreads();   // previous compute done reading LDS
        As[lk + 0][lr] = av.x; As[lk + 1][lr] = av.y;
        As[lk + 2][lr] = av.z; As[lk + 3][lr] = av.w;
        Bs[lk + 0][lr] = bv.x; Bs[lk + 1][lr] = bv.y;
        Bs[lk + 2][lr] = bv.z; Bs[lk + 3][lr] = bv.w;
        __syncthreads();

        if (kt + 1 < NT) {   // prefetch next tiles while computing
            av = *reinterpret_cast<const float4*>(Aptr + (kt + 1) * 16);
            bv = *reinterpret_cast<const float4*>(Bptr + (kt + 1) * 16);
        }

        #pragma unroll
        for (int k = 0; k < 16; ++k) {
            float4 a = *reinterpret_cast<const float4*>(&As[k][ty * 4]);
            float4 bb = *reinterpret_cast<const float4*>(&Bs[k][tx * 4]);
            acc[0][0] = fmaf(a.x, bb.x, acc[0][0]);
            acc[0][1] = fmaf(a.x, bb.y, acc[0][1]);
            acc[0][2] = fmaf(a.x, bb.z, acc[0][2]);
            acc[0][3] = fmaf(a.x, bb.w, acc[0][3]);
            acc[1][0] = fmaf(a.y, bb.x, acc[1][0]);
            acc[1][1] = fmaf(a.y, bb.y, acc[1][1]);
            acc[1][2] = fmaf(a.y, bb.z, acc[1][2]);
            acc[1][3] = fmaf(a.y, bb.w, acc[1][3]);
            acc[2][0] = fmaf(a.z, bb.x, acc[2][0]);
            acc[2][1] = fmaf(a.z, bb.y, acc[2][1]);
            acc[2][2] = fmaf(a.z, bb.z, acc[2][2]);
            acc[2][3] = fmaf(a.z, bb.w, acc[2][3]);
            acc[3][0] = fmaf(a.w, bb.x, acc[3][0]);
            acc[3][1] = fmaf(a.w, bb.y, acc[3][1]);
            acc[3][2] = fmaf(a.w, bb.z, acc[3][2]);
            acc[3][3] = fmaf(a.w, bb.w, acc[3][3]);
        }
    }

    const float4 bb = *reinterpret_cast<const float4*>(&bias[col0 + tx * 4]);
    #pragma unroll
    for (int i = 0; i < 4; ++i) {
        float4 o;
        o.x = acc[i][0] + bb.x;
        o.y = acc[i][1] + bb.y;
        o.z = acc[i][2] + bb.z;
        o.w = acc[i][3] + bb.w;
        *reinterpret_cast<float4*>(&C[(size_t)(row0 + ty * 4 + i) * N + col0 + tx * 4]) = o;
    }
}

// =====================================================================
extern "C" void kernel_launch(void* const* d_in, const int* in_sizes, int n_in,
                              void* d_out, int out_size, void* d_ws, size_t ws_size,
                              hipStream_t stream)
{
    const float* x   = (const float*)d_in[0];  // (4,1024,512)
    const float* W1  = (const float*)d_in[1];  // (2048,512)
    const float* b1  = (const float*)d_in[2];  // (2048)
    const float* W2  = (const float*)d_in[3];  // (512,2048)
    const float* b2  = (const float*)d_in[4];  // (512)
    const float* Lam = (const float*)d_in[5];  // (2048,512)
    const float* Gam = (const float*)d_in[6];  // (2048,512)
    float* out  = (float*)d_out;               // (4,1024,512)
    float* hbuf = (float*)d_ws;                // (4096, 2048) f32 = 32 MB

    // Scan: 512 blocks x 256 threads
    stp_scan<<<dim3(BSZ * (DFF / 16)), dim3(256), 0, stream>>>(x, W1, b1, Lam, Gam, hbuf);

    // out = h @ W2^T + b2 : M=4096, N=512, K=2048
    dim3 g2(DM / 64, (BSZ * LSEQ) / 64);   // (8, 64)
    gemm_nt_bias<<<g2, dim3(256), 0, stream>>>(hbuf, W2, b2, out, BSZ * LSEQ, DM, DFF);
}